// Round 13
// baseline (371.703 us; speedup 1.0000x reference)
//
#include <hip/hip_runtime.h>
#include <math.h>

typedef __attribute__((ext_vector_type(8))) short bf16x8;
typedef __attribute__((ext_vector_type(4))) float f32x4;

#define Bdim 128
#define Cdim 12
#define Ddim 128
#define Tdim 256
#define TOn  8
#define TIn  64
#define Sn   183
#define DENOMF 187392.0f
#define NEG_INF -3.402823466e38f

// ---------------- workspace layout (bytes) ----------------
#define OFFB_ENC 0
#define OFFB_CTX 8388608
#define OFFB_GI  16777216
#define OFFB_BCT 67108864
#define OFFB_WT  67305472
#define OFFB_LP  67403776
#define OFFB_CP  67409632
#define OFFB_WHP 67415488   // W_hh packed bf16 pairs: 384 rows x 64 u32 = 98304 B
#define OFFB_PWB 67513792   // pred_W bf16: 8*128*128*2 = 262144 B

__device__ __forceinline__ float frcp(float x) { return __builtin_amdgcn_rcpf(x); }

__device__ __forceinline__ unsigned short f2b(float x) {
    unsigned int u = __builtin_bit_cast(unsigned int, x);
    u += 0x7FFFu + ((u >> 16) & 1u);
    return (unsigned short)(u >> 16);
}
__device__ __forceinline__ unsigned int pk2(float a, float b) {
    return (unsigned int)f2b(a) | ((unsigned int)f2b(b) << 16);
}

// opaque loads: compiler cannot rematerialize these inside loops.
__device__ __forceinline__ uint4 ldg4u_pin(const unsigned int* p) {
    uint4 r;
    asm volatile("global_load_dwordx4 %0, %1, off\n\ts_waitcnt vmcnt(0)"
                 : "=v"(r) : "v"(p) : "memory");
    return r;
}

// ---------------- prep: weight transposes -> bf16 ----------------
__global__ __launch_bounds__(256) void k_prep(const float* __restrict__ conv_w,
                                              unsigned short* __restrict__ BcT,
                                              const float* __restrict__ W_ih,
                                              unsigned short* __restrict__ Wt,
                                              const float* __restrict__ W_hh,
                                              unsigned int* __restrict__ Whp,
                                              const float* __restrict__ pW,
                                              unsigned short* __restrict__ pWb) {
    int id = blockIdx.x * 256 + threadIdx.x;
    if (id < 128 * 768) {
        int d = id / 768, klin = id % 768;
        int kt = klin / 12, c = klin % 12;
        BcT[id] = f2b(conv_w[d * 768 + c * 64 + kt]);   // BcT[d][kt*12+c]
    }
    if (id < 384 * 128) Wt[id] = f2b(W_ih[id]);          // Wt[n][k]
    if (id < 384 * 64) {
        int row = id >> 6, k2 = id & 63;
        Whp[id] = pk2(W_hh[row * 128 + 2 * k2], W_hh[row * 128 + 2 * k2 + 1]);
    }
    if (id < 8 * 128 * 128) pWb[id] = f2b(pW[id]);       // pred_W -> bf16
}

// ---------------- conv as bf16 MFMA GEMM ----------------
__global__ __launch_bounds__(256) void k_conv(const float* __restrict__ X,
                                              const unsigned short* __restrict__ BcT,
                                              const float* __restrict__ conv_b,
                                              unsigned short* __restrict__ encb) {
    const int t = blockIdx.x;
    __shared__ __align__(16) char As[16384];   // [b=128][k=64] bf16, swizzled
    __shared__ __align__(16) char Bs[16384];   // [d=128][k=64] bf16, swizzled
    const int tid = threadIdx.x;
    const int lane = tid & 63, wid = tid >> 6;
    const int wy = wid >> 1, wx = wid & 1;
    const int g = lane >> 4, ln = lane & 15;

    f32x4 acc[4][4];
#pragma unroll
    for (int i = 0; i < 4; ++i)
#pragma unroll
        for (int j = 0; j < 4; ++j) acc[i][j] = (f32x4){0.f, 0.f, 0.f, 0.f};

    for (int kc = 0; kc < 768; kc += 64) {
        __syncthreads();
#pragma unroll
        for (int it = 0; it < 4; ++it) {
            int G = tid + it * 256;             // granule 0..1023 (16B each)
            int r = G >> 3, go = G & 7;
            const float* src = X + (size_t)r * (16384 * 12) + t * 768 + kc + go * 8;
            float4 f0 = *(const float4*)src;
            float4 f1 = *(const float4*)(src + 4);
            uint4 w; w.x = pk2(f0.x, f0.y); w.y = pk2(f0.z, f0.w);
            w.z = pk2(f1.x, f1.y); w.w = pk2(f1.z, f1.w);
            *(uint4*)(As + (r * 8 + (go ^ (r & 7))) * 16) = w;
            uint4 v = *(const uint4*)(BcT + (size_t)r * 768 + kc + go * 8);
            *(uint4*)(Bs + (r * 8 + (go ^ (r & 7))) * 16) = v;
        }
        __syncthreads();
#pragma unroll
        for (int ks = 0; ks < 2; ++ks) {
            bf16x8 af[4], bfr[4];
            const int kb = ks * 64 + g * 16;
#pragma unroll
            for (int mi = 0; mi < 4; ++mi) {
                int r = wy * 64 + mi * 16 + ln;
                af[mi] = *(const bf16x8*)(As + r * 128 + (kb ^ ((r & 7) << 4)));
            }
#pragma unroll
            for (int ni = 0; ni < 4; ++ni) {
                int r = wx * 64 + ni * 16 + ln;
                bfr[ni] = *(const bf16x8*)(Bs + r * 128 + (kb ^ ((r & 7) << 4)));
            }
#pragma unroll
            for (int mi = 0; mi < 4; ++mi)
#pragma unroll
                for (int ni = 0; ni < 4; ++ni)
                    acc[mi][ni] = __builtin_amdgcn_mfma_f32_16x16x32_bf16(af[mi], bfr[ni], acc[mi][ni], 0, 0, 0);
        }
    }
    float cb[4];
#pragma unroll
    for (int ni = 0; ni < 4; ++ni) cb[ni] = conv_b[wx * 64 + ni * 16 + ln];
    unsigned short* dst = encb + (size_t)t * (128 * 128);
#pragma unroll
    for (int mi = 0; mi < 4; ++mi)
#pragma unroll
        for (int jj = 0; jj < 4; ++jj) {
            int b = wy * 64 + mi * 16 + g * 4 + jj;
#pragma unroll
            for (int ni = 0; ni < 4; ++ni) {
                int d = wx * 64 + ni * 16 + ln;
                dst[b * 128 + d] = f2b(fmaxf(acc[mi][ni][jj] + cb[ni], 0.f));
            }
        }
}

// ---------------- gi2 = enc @ W_ih^T + biases, layout [t][gate][g][batch] ----------------
__global__ __launch_bounds__(256) void k_gi(const unsigned short* __restrict__ encb,
                                            const unsigned short* __restrict__ Wt,
                                            const float* __restrict__ b_ih,
                                            const float* __restrict__ b_hh,
                                            float* __restrict__ gi2) {
    const int mt = blockIdx.x, nt = blockIdx.y;
    __shared__ __align__(16) char As[32768];   // [m=128][k=128]
    __shared__ __align__(16) char Bs[32768];   // [n=128][k=128]
    const int tid = threadIdx.x;
    const int lane = tid & 63, wid = tid >> 6;
    const int wy = wid >> 1, wx = wid & 1;
    const int g = lane >> 4, ln = lane & 15;

    {
        const unsigned short* asrc = encb + (size_t)mt * (128 * 128);
        const unsigned short* bsrc = Wt + (size_t)nt * (128 * 128);
#pragma unroll
        for (int it = 0; it < 8; ++it) {
            int G = tid + it * 256;             // granule 0..2047
            int r = G >> 4, go = G & 15;
            *(uint4*)(As + (r * 16 + (go ^ (r & 7))) * 16) = *(const uint4*)(asrc + r * 128 + go * 8);
            *(uint4*)(Bs + (r * 16 + (go ^ (r & 7))) * 16) = *(const uint4*)(bsrc + r * 128 + go * 8);
        }
    }
    __syncthreads();

    f32x4 acc[4][4];
#pragma unroll
    for (int i = 0; i < 4; ++i)
#pragma unroll
        for (int j = 0; j < 4; ++j) acc[i][j] = (f32x4){0.f, 0.f, 0.f, 0.f};
#pragma unroll
    for (int ks = 0; ks < 4; ++ks) {
        bf16x8 af[4], bfr[4];
        const int kb = ks * 64 + g * 16;
#pragma unroll
        for (int mi = 0; mi < 4; ++mi) {
            int r = wy * 64 + mi * 16 + ln;
            af[mi] = *(const bf16x8*)(As + r * 256 + (kb ^ ((r & 7) << 4)));
        }
#pragma unroll
        for (int ni = 0; ni < 4; ++ni) {
            int r = wx * 64 + ni * 16 + ln;
            bfr[ni] = *(const bf16x8*)(Bs + r * 256 + (kb ^ ((r & 7) << 4)));
        }
#pragma unroll
        for (int mi = 0; mi < 4; ++mi)
#pragma unroll
            for (int ni = 0; ni < 4; ++ni)
                acc[mi][ni] = __builtin_amdgcn_mfma_f32_16x16x32_bf16(af[mi], bfr[ni], acc[mi][ni], 0, 0, 0);
    }
    float bv[4];
#pragma unroll
    for (int ni = 0; ni < 4; ++ni) {
        int n = nt * 128 + wx * 64 + ni * 16 + ln;
        bv[ni] = b_ih[n] + (n < 256 ? b_hh[n] : 0.f);   // fold b_hh for r,z gates
    }
#pragma unroll
    for (int mi = 0; mi < 4; ++mi)
#pragma unroll
        for (int ni = 0; ni < 4; ++ni) {
            int gout = wx * 64 + ni * 16 + ln;          // n % 128
            int brow = wy * 64 + mi * 16 + g * 4;       // batch base (4 consecutive)
            float4 st;
            st.x = acc[mi][ni][0] + bv[ni];
            st.y = acc[mi][ni][1] + bv[ni];
            st.z = acc[mi][ni][2] + bv[ni];
            st.w = acc[mi][ni][3] + bv[ni];
            *(float4*)(gi2 + ((size_t)(mt * 3 + nt) * 128 + gout) * 128 + brow) = st;
        }
}

// ---------------- GRU v11: MFMA recurrence ----------------
// 8 blocks x 512 thr. Block bb: batches bb*16..+16. Wave w owns g in [16w,16w+16)
// (N-tiles {w, 8+w, 16+w} = gates r,z,n for the same g). h in double-buffered
// swizzled LDS [16][128] bf16; W_hh fragments in 48 VGPRs; gi2 float4 inits the
// MFMA accumulator (C-operand). Gates lane-local, fp32 hold feedback.
__global__ __launch_bounds__(512)
__attribute__((amdgpu_waves_per_eu(2, 2)))
void k_gru(const float* __restrict__ gi2,
           const unsigned int* __restrict__ Whp,
           const float* __restrict__ bhh,
           unsigned short* __restrict__ ctxb,
           float* __restrict__ out_hidden) {
    const int bb = blockIdx.x;
    const int tid = threadIdx.x;
    const int w = tid >> 6, l = tid & 63;
    const int gl = l & 15, q = l >> 4;
    const int g = w * 16 + gl;                 // hidden index this lane owns (C col)
    __shared__ __align__(16) char hlds[2][4096];   // [16 batch][256B], byte ^= (row&7)<<4

    // W_hh B-fragments, loaded once: lane l needs W_hh[n][k] k=kt*32+q*8..+8 (4 u32)
    bf16x8 bR[4], bZ[4], bN[4];
#pragma unroll
    for (int kt = 0; kt < 4; ++kt) {
        bR[kt] = __builtin_bit_cast(bf16x8, ldg4u_pin(Whp + (size_t)(g) * 64 + kt * 16 + q * 4));
        bZ[kt] = __builtin_bit_cast(bf16x8, ldg4u_pin(Whp + (size_t)(128 + g) * 64 + kt * 16 + q * 4));
        bN[kt] = __builtin_bit_cast(bf16x8, ldg4u_pin(Whp + (size_t)(256 + g) * 64 + kt * 16 + q * 4));
    }
    const float bh2 = bhh[256 + g];

    if (tid < 256) *(uint4*)(hlds[0] + tid * 16) = (uint4){0u, 0u, 0u, 0u};

    // gi2 prefetch (depth 2): per gate one float4 = [4 batches] at (t, gate, g)
    const float* gbase = gi2 + (size_t)(bb * 16 + q * 4);
#define GI_PTR(T, G) (gbase + ((size_t)((T) * 3 + (G)) * 128 + g) * 128)
    f32x4 gR0 = *(const f32x4*)GI_PTR(0, 0), gZ0 = *(const f32x4*)GI_PTR(0, 1), gN0 = *(const f32x4*)GI_PTR(0, 2);
    f32x4 gR1 = *(const f32x4*)GI_PTR(1, 0), gZ1 = *(const f32x4*)GI_PTR(1, 1), gN1 = *(const f32x4*)GI_PTR(1, 2);
    float hold[4] = {0.f, 0.f, 0.f, 0.f};
    __syncthreads();

    for (int t = 0; t < 256; ++t) {
        const int cur = t & 1;
        f32x4 gR2 = (f32x4){0.f,0.f,0.f,0.f}, gZ2 = gR2, gN2 = gR2;
        if (t + 2 < 256) {
            gR2 = *(const f32x4*)GI_PTR(t + 2, 0);
            gZ2 = *(const f32x4*)GI_PTR(t + 2, 1);
            gN2 = *(const f32x4*)GI_PTR(t + 2, 2);
        }

        // A fragments: row = gl (batch), k = kt*32 + q*8 (bf16), swizzled
        const char* hcur = hlds[cur];
        bf16x8 af[4];
#pragma unroll
        for (int kt = 0; kt < 4; ++kt)
            af[kt] = *(const bf16x8*)(hcur + gl * 256 + ((kt * 64 + q * 16) ^ ((gl & 7) << 4)));

        f32x4 aR = gR0, aZ = gZ0;
        f32x4 aN = (f32x4){bh2, bh2, bh2, bh2};
#pragma unroll
        for (int kt = 0; kt < 4; ++kt) {
            aR = __builtin_amdgcn_mfma_f32_16x16x32_bf16(af[kt], bR[kt], aR, 0, 0, 0);
            aZ = __builtin_amdgcn_mfma_f32_16x16x32_bf16(af[kt], bZ[kt], aZ, 0, 0, 0);
            aN = __builtin_amdgcn_mfma_f32_16x16x32_bf16(af[kt], bN[kt], aN, 0, 0, 0);
        }

        char* hnxt = hlds[cur ^ 1];
#pragma unroll
        for (int jj = 0; jj < 4; ++jj) {
            float r = frcp(1.f + __expf(-aR[jj]));
            float z = frcp(1.f + __expf(-aZ[jj]));
            float xn = gN0[jj] + r * aN[jj];
            xn = fmaxf(xn, -20.f);
            float e2 = __expf(-2.f * xn);
            float n = (1.f - e2) * frcp(1.f + e2);
            float hnew = (1.f - z) * n + z * hold[jj];
            hold[jj] = hnew;
            const int brow = q * 4 + jj;
            unsigned short hb = f2b(hnew);
            *(unsigned short*)(hnxt + brow * 256 + ((g * 2) ^ ((brow & 7) << 4))) = hb;
            ctxb[((size_t)t * 128 + bb * 16 + brow) * 128 + g] = hb;
            if (t == 255) out_hidden[(bb * 16 + brow) * 128 + g] = hnew;
        }

        gR0 = gR1; gZ0 = gZ1; gN0 = gN1;
        gR1 = gR2; gZ1 = gZ2; gN1 = gN2;
        asm volatile("s_waitcnt lgkmcnt(0)" ::: "memory");
        __builtin_amdgcn_s_barrier();
    }
#undef GI_PTR
}

// ---------------- fused CPC: MFMA GEMM1 (P^T) -> MFMA GEMM2 (Sc) -> reg softmax ----------------
__global__ __launch_bounds__(256) void k_cpc(const unsigned short* __restrict__ ctxb,
                                             const unsigned short* __restrict__ encb,
                                             const unsigned short* __restrict__ pWb,
                                             const float* __restrict__ pb,
                                             float* __restrict__ lp,
                                             float* __restrict__ cp) {
    const int o = blockIdx.x, s = blockIdx.y;
    __shared__ __align__(16) char bufA[32768];   // ctx [c][d] -> later tgt [b][e]
    __shared__ __align__(16) char bufB[32768];   // Wo  [e][d] -> later P   [c][e]
    __shared__ float rowm[2][128], rowsum[2][128];
    __shared__ float Lrow[128], diagv[128];
    __shared__ float colv[2][128];
    __shared__ int   colix[2][128];
    __shared__ float fin[4];

    const int tid = threadIdx.x;
    const int lane = tid & 63, wid = tid >> 6;
    const int wy = wid >> 1, wx = wid & 1;
    const int g = lane >> 4, ln = lane & 15;

    {
        const unsigned short* src = ctxb + (size_t)(TIn + s) * (128 * 128);
        const unsigned short* wsrc = pWb + (size_t)o * (128 * 128);
#pragma unroll
        for (int it = 0; it < 8; ++it) {
            int G = tid + it * 256;
            int r = G >> 4, go = G & 15;
            *(uint4*)(bufA + (r * 16 + (go ^ (r & 7))) * 16) = *(const uint4*)(src + r * 128 + go * 8);
            *(uint4*)(bufB + (r * 16 + (go ^ (r & 7))) * 16) = *(const uint4*)(wsrc + r * 128 + go * 8);
        }
    }
    __syncthreads();

    // GEMM1: P^T[e][c] = Wo[e][:] . ctx[c][:]
    f32x4 acc[4][4];
#pragma unroll
    for (int i = 0; i < 4; ++i)
#pragma unroll
        for (int j = 0; j < 4; ++j) acc[i][j] = (f32x4){0.f, 0.f, 0.f, 0.f};
#pragma unroll
    for (int ks = 0; ks < 4; ++ks) {
        bf16x8 af[4], bfr[4];
        const int kb = ks * 64 + g * 16;
#pragma unroll
        for (int mi = 0; mi < 4; ++mi) {
            int r = wy * 64 + mi * 16 + ln;
            af[mi] = *(const bf16x8*)(bufB + r * 256 + (kb ^ ((r & 7) << 4)));
        }
#pragma unroll
        for (int ni = 0; ni < 4; ++ni) {
            int r = wx * 64 + ni * 16 + ln;
            bfr[ni] = *(const bf16x8*)(bufA + r * 256 + (kb ^ ((r & 7) << 4)));
        }
#pragma unroll
        for (int mi = 0; mi < 4; ++mi)
#pragma unroll
            for (int ni = 0; ni < 4; ++ni)
                acc[mi][ni] = __builtin_amdgcn_mfma_f32_16x16x32_bf16(af[mi], bfr[ni], acc[mi][ni], 0, 0, 0);
    }
    __syncthreads();

    // write P[c][e] (bias, bf16, swizzled) into bufB; stage tgt into bufA
    {
        float pbv[4][4];
#pragma unroll
        for (int mi = 0; mi < 4; ++mi) {
            int e0 = wy * 64 + mi * 16 + g * 4;
#pragma unroll
            for (int jj = 0; jj < 4; ++jj) pbv[mi][jj] = pb[o * 128 + e0 + jj];
        }
#pragma unroll
        for (int mi = 0; mi < 4; ++mi) {
            int e0 = wy * 64 + mi * 16 + g * 4;
#pragma unroll
            for (int ni = 0; ni < 4; ++ni) {
                int c = wx * 64 + ni * 16 + ln;
                unsigned int lo = pk2(acc[mi][ni][0] + pbv[mi][0], acc[mi][ni][1] + pbv[mi][1]);
                unsigned int hi = pk2(acc[mi][ni][2] + pbv[mi][2], acc[mi][ni][3] + pbv[mi][3]);
                int byteoff = c * 256 + ((e0 * 2) ^ ((c & 7) << 4));
                *(uint2*)(bufB + byteoff) = make_uint2(lo, hi);
            }
        }
        const unsigned short* tsrc = encb + (size_t)(TIn + 1 + o + s) * (128 * 128);
#pragma unroll
        for (int it = 0; it < 8; ++it) {
            int G = tid + it * 256;
            int r = G >> 4, go = G & 15;
            *(uint4*)(bufA + (r * 16 + (go ^ (r & 7))) * 16) = *(const uint4*)(tsrc + r * 128 + go * 8);
        }
    }
    __syncthreads();

    // GEMM2: Sc[b][c] = tgt[b][:] . P[c][:]
#pragma unroll
    for (int i = 0; i < 4; ++i)
#pragma unroll
        for (int j = 0; j < 4; ++j) acc[i][j] = (f32x4){0.f, 0.f, 0.f, 0.f};
#pragma unroll
    for (int ks = 0; ks < 4; ++ks) {
        bf16x8 af[4], bfr[4];
        const int kb = ks * 64 + g * 16;
#pragma unroll
        for (int mi = 0; mi < 4; ++mi) {
            int r = wy * 64 + mi * 16 + ln;
            af[mi] = *(const bf16x8*)(bufA + r * 256 + (kb ^ ((r & 7) << 4)));
        }
#pragma unroll
        for (int ni = 0; ni < 4; ++ni) {
            int r = wx * 64 + ni * 16 + ln;
            bfr[ni] = *(const bf16x8*)(bufB + r * 256 + (kb ^ ((r & 7) << 4)));
        }
#pragma unroll
        for (int mi = 0; mi < 4; ++mi)
#pragma unroll
            for (int ni = 0; ni < 4; ++ni)
                acc[mi][ni] = __builtin_amdgcn_mfma_f32_16x16x32_bf16(af[mi], bfr[ni], acc[mi][ni], 0, 0, 0);
    }

    // row softmax stats + diag, in-register
#pragma unroll
    for (int mi = 0; mi < 4; ++mi) {
#pragma unroll
        for (int jj = 0; jj < 4; ++jj) {
            float m = fmaxf(fmaxf(acc[mi][0][jj], acc[mi][1][jj]),
                            fmaxf(acc[mi][2][jj], acc[mi][3][jj]));
            m = fmaxf(m, __shfl_xor(m, 1)); m = fmaxf(m, __shfl_xor(m, 2));
            m = fmaxf(m, __shfl_xor(m, 4)); m = fmaxf(m, __shfl_xor(m, 8));
            float sm = __expf(acc[mi][0][jj] - m) + __expf(acc[mi][1][jj] - m)
                     + __expf(acc[mi][2][jj] - m) + __expf(acc[mi][3][jj] - m);
            sm += __shfl_xor(sm, 1); sm += __shfl_xor(sm, 2);
            sm += __shfl_xor(sm, 4); sm += __shfl_xor(sm, 8);
            int b = wy * 64 + mi * 16 + g * 4 + jj;
            if (ln == 0) { rowm[wx][b] = m; rowsum[wx][b] = sm; }
            if (wy == wx && ln == g * 4 + jj) diagv[b] = acc[mi][mi][jj];
        }
    }
    __syncthreads();
    if (tid < 128) {
        float m0 = rowm[0][tid], m1 = rowm[1][tid];
        float mm = fmaxf(m0, m1);
        float ss = rowsum[0][tid] * __expf(m0 - mm) + rowsum[1][tid] * __expf(m1 - mm);
        Lrow[tid] = mm + __logf(ss);
    }
    __syncthreads();

    float Lr[4][4];
#pragma unroll
    for (int mi = 0; mi < 4; ++mi)
#pragma unroll
        for (int jj = 0; jj < 4; ++jj) Lr[mi][jj] = Lrow[wy * 64 + mi * 16 + g * 4 + jj];

#pragma unroll
    for (int ni = 0; ni < 4; ++ni) {
        float best = NEG_INF; int bidx = 0x7fffffff;
#pragma unroll
        for (int mi = 0; mi < 4; ++mi)
#pragma unroll
            for (int jj = 0; jj < 4; ++jj) {
                float v = acc[mi][ni][jj] - Lr[mi][jj];
                int r = wy * 64 + mi * 16 + g * 4 + jj;
                if (v > best) { best = v; bidx = r; }
            }
#pragma unroll
        for (int mask = 16; mask <= 32; mask <<= 1) {
            float ov = __shfl_xor(best, mask);
            int   oi = __shfl_xor(bidx, mask);
            if (ov > best || (ov == best && oi < bidx)) { best = ov; bidx = oi; }
        }
        if (g == 0) {
            int c = wx * 64 + ni * 16 + ln;
            colv[wy][c] = best; colix[wy][c] = bidx;
        }
    }
    __syncthreads();

    float lsum = 0.f, csum = 0.f;
    if (tid < 128) {
        lsum = diagv[tid] - Lrow[tid];
        float v0 = colv[0][tid], v1 = colv[1][tid];
        int ix = (v1 > v0) ? colix[1][tid] : colix[0][tid];
        csum = (ix == tid) ? 1.f : 0.f;
    }
#pragma unroll
    for (int off = 32; off > 0; off >>= 1) {
        lsum += __shfl_down(lsum, off);
        csum += __shfl_down(csum, off);
    }
    if (lane == 0 && wid < 2) { fin[wid] = lsum; fin[2 + wid] = csum; }
    __syncthreads();
    if (tid == 0) {
        lp[o * Sn + s] = fin[0] + fin[1];
        cp[o * Sn + s] = fin[2] + fin[3];
    }
}

// ---------------- final reduction ----------------
__global__ __launch_bounds__(256) void k_final(const float* __restrict__ lp,
                                               const float* __restrict__ cp,
                                               float* __restrict__ out) {
    __shared__ float sl[256], sc2[256];
    const int tid = threadIdx.x;
    float l = 0.f, c = 0.f;
    for (int i = tid; i < TOn * Sn; i += 256) { l += lp[i]; c += cp[i]; }
    sl[tid] = l; sc2[tid] = c;
    __syncthreads();
    for (int s = 128; s > 0; s >>= 1) {
        if (tid < s) { sl[tid] += sl[tid + s]; sc2[tid] += sc2[tid + s]; }
        __syncthreads();
    }
    if (tid == 0) {
        out[0] = sc2[0] / DENOMF;      // accuracy
        out[1] = -sl[0] / DENOMF;      // loss
    }
}

extern "C" void kernel_launch(void* const* d_in, const int* in_sizes, int n_in,
                              void* d_out, int out_size, void* d_ws, size_t ws_size,
                              hipStream_t stream) {
    const float* X      = (const float*)d_in[0];
    const float* conv_w = (const float*)d_in[1];
    const float* conv_b = (const float*)d_in[2];
    const float* W_ih   = (const float*)d_in[3];
    const float* W_hh   = (const float*)d_in[4];
    const float* b_ih   = (const float*)d_in[5];
    const float* b_hh   = (const float*)d_in[6];
    const float* pred_W = (const float*)d_in[7];
    const float* pred_b = (const float*)d_in[8];
    float* out = (float*)d_out;
    char*  ws  = (char*)d_ws;

    unsigned short* encb = (unsigned short*)(ws + OFFB_ENC);
    unsigned short* ctxb = (unsigned short*)(ws + OFFB_CTX);
    float*          gi2  = (float*)(ws + OFFB_GI);
    unsigned short* BcT  = (unsigned short*)(ws + OFFB_BCT);
    unsigned short* Wt   = (unsigned short*)(ws + OFFB_WT);
    float*          lp   = (float*)(ws + OFFB_LP);
    float*          cp   = (float*)(ws + OFFB_CP);
    unsigned int*   Whp  = (unsigned int*)(ws + OFFB_WHP);
    unsigned short* pWb  = (unsigned short*)(ws + OFFB_PWB);

    k_prep <<<dim3(512),     dim3(256), 0, stream>>>(conv_w, BcT, W_ih, Wt, W_hh, Whp, pred_W, pWb);
    k_conv <<<dim3(256),     dim3(256), 0, stream>>>(X, BcT, conv_b, encb);
    k_gi   <<<dim3(256, 3),  dim3(256), 0, stream>>>(encb, Wt, b_ih, b_hh, gi2);
    k_gru  <<<dim3(8),       dim3(512), 0, stream>>>(gi2, Whp, b_hh, ctxb, out + 2);
    k_cpc  <<<dim3(TOn, Sn), dim3(256), 0, stream>>>(ctxb, encb, pWb, pred_b, lp, cp);
    k_final<<<dim3(1),       dim3(256), 0, stream>>>(lp, cp, out);
}

// Round 14
// 223.839 us; speedup vs baseline: 1.6606x; 1.6606x over previous
//
#include <hip/hip_runtime.h>
#include <math.h>

typedef __attribute__((ext_vector_type(8))) short bf16x8;
typedef __attribute__((ext_vector_type(4))) float f32x4;

#define Bdim 128
#define Cdim 12
#define Ddim 128
#define Tdim 256
#define TOn  8
#define TIn  64
#define Sn   183
#define DENOMF 187392.0f
#define NEG_INF -3.402823466e38f

// ---------------- workspace layout (bytes) ----------------
#define OFFB_ENC 0
#define OFFB_CTX 8388608
#define OFFB_GI  16777216
#define OFFB_BCT 67108864
#define OFFB_WT  67305472
#define OFFB_LP  67403776
#define OFFB_CP  67409632
#define OFFB_WHP 67415488   // W_hh packed bf16 pairs: 384 rows x 64 u32 = 98304 B
#define OFFB_PWB 67513792   // pred_W bf16: 8*128*128*2 = 262144 B

__device__ __forceinline__ float frcp(float x) { return __builtin_amdgcn_rcpf(x); }

__device__ __forceinline__ unsigned short f2b(float x) {
    unsigned int u = __builtin_bit_cast(unsigned int, x);
    u += 0x7FFFu + ((u >> 16) & 1u);
    return (unsigned short)(u >> 16);
}
__device__ __forceinline__ unsigned int pk2(float a, float b) {
    return (unsigned int)f2b(a) | ((unsigned int)f2b(b) << 16);
}

// opaque loads: compiler cannot rematerialize these inside loops.
__device__ __forceinline__ uint4 ldg4u_pin(const unsigned int* p) {
    uint4 r;
    asm volatile("global_load_dwordx4 %0, %1, off\n\ts_waitcnt vmcnt(0)"
                 : "=v"(r) : "v"(p) : "memory");
    return r;
}

// D = dot2(bf16x2 a, bf16x2 b) + acc   (f32 accumulate)
__device__ __forceinline__ void dot2b(float& acc, unsigned int a, unsigned int b) {
    asm("v_dot2_f32_bf16 %0, %1, %2, %0" : "+v"(acc) : "v"(a), "v"(b));
}

// quad_perm DPP butterflies (VALU, ~2cy) — q-group is exactly a DPP quad (q = lane&3)
__device__ __forceinline__ float dpp_xor1(float x) {
    return __builtin_bit_cast(float, __builtin_amdgcn_mov_dpp(
        __builtin_bit_cast(int, x), 0xB1, 0xF, 0xF, true));   // [1,0,3,2]
}
__device__ __forceinline__ float dpp_xor2(float x) {
    return __builtin_bit_cast(float, __builtin_amdgcn_mov_dpp(
        __builtin_bit_cast(int, x), 0x4E, 0xF, 0xF, true));   // [2,3,0,1]
}

// ---------------- prep: weight transposes -> bf16 ----------------
__global__ __launch_bounds__(256) void k_prep(const float* __restrict__ conv_w,
                                              unsigned short* __restrict__ BcT,
                                              const float* __restrict__ W_ih,
                                              unsigned short* __restrict__ Wt,
                                              const float* __restrict__ W_hh,
                                              unsigned int* __restrict__ Whp,
                                              const float* __restrict__ pW,
                                              unsigned short* __restrict__ pWb) {
    int id = blockIdx.x * 256 + threadIdx.x;
    if (id < 128 * 768) {
        int d = id / 768, klin = id % 768;
        int kt = klin / 12, c = klin % 12;
        BcT[id] = f2b(conv_w[d * 768 + c * 64 + kt]);   // BcT[d][kt*12+c]
    }
    if (id < 384 * 128) Wt[id] = f2b(W_ih[id]);          // Wt[n][k]
    if (id < 384 * 64) {
        int row = id >> 6, k2 = id & 63;
        Whp[id] = pk2(W_hh[row * 128 + 2 * k2], W_hh[row * 128 + 2 * k2 + 1]);
    }
    if (id < 8 * 128 * 128) pWb[id] = f2b(pW[id]);       // pred_W -> bf16
}

// ---------------- fused conv + gi: one block per t ----------------
// Phase 1: enc[t] = relu(X_slice . BcT + conv_b)  (128x768x128 MFMA GEMM)
// Phase 2: gi[t*128+b][n] = enc[t] @ W_ih^T + biases, reusing enc tile from LDS
__global__ __launch_bounds__(256) void k_convgi(const float* __restrict__ X,
                                                const unsigned short* __restrict__ BcT,
                                                const float* __restrict__ conv_b,
                                                const unsigned short* __restrict__ Wt,
                                                const float* __restrict__ b_ih,
                                                const float* __restrict__ b_hh,
                                                unsigned short* __restrict__ encb,
                                                float* __restrict__ gi) {
    const int t = blockIdx.x;
    __shared__ __align__(16) char smem[65536];
    char* As   = smem;              // conv A [128 b][64 k]  (16KB); later gi B-tile (32KB)
    char* Bs   = smem + 16384;      // conv B [128 d][64 k]  (16KB)
    char* encL = smem + 32768;      // enc    [128 b][128 d] (32KB), gi A-tile
    const int tid = threadIdx.x;
    const int lane = tid & 63, wid = tid >> 6;
    const int wy = wid >> 1, wx = wid & 1;
    const int g = lane >> 4, ln = lane & 15;

    f32x4 acc[4][4];
#pragma unroll
    for (int i = 0; i < 4; ++i)
#pragma unroll
        for (int j = 0; j < 4; ++j) acc[i][j] = (f32x4){0.f, 0.f, 0.f, 0.f};

    for (int kc = 0; kc < 768; kc += 64) {
        __syncthreads();
#pragma unroll
        for (int it = 0; it < 4; ++it) {
            int G = tid + it * 256;             // granule 0..1023 (16B each)
            int r = G >> 3, go = G & 7;
            const float* src = X + (size_t)r * (16384 * 12) + t * 768 + kc + go * 8;
            float4 f0 = *(const float4*)src;
            float4 f1 = *(const float4*)(src + 4);
            uint4 w; w.x = pk2(f0.x, f0.y); w.y = pk2(f0.z, f0.w);
            w.z = pk2(f1.x, f1.y); w.w = pk2(f1.z, f1.w);
            *(uint4*)(As + (r * 8 + (go ^ (r & 7))) * 16) = w;
            uint4 v = *(const uint4*)(BcT + (size_t)r * 768 + kc + go * 8);
            *(uint4*)(Bs + (r * 8 + (go ^ (r & 7))) * 16) = v;
        }
        __syncthreads();
#pragma unroll
        for (int ks = 0; ks < 2; ++ks) {
            bf16x8 af[4], bfr[4];
            const int kb = ks * 64 + g * 16;
#pragma unroll
            for (int mi = 0; mi < 4; ++mi) {
                int r = wy * 64 + mi * 16 + ln;
                af[mi] = *(const bf16x8*)(As + r * 128 + (kb ^ ((r & 7) << 4)));
            }
#pragma unroll
            for (int ni = 0; ni < 4; ++ni) {
                int r = wx * 64 + ni * 16 + ln;
                bfr[ni] = *(const bf16x8*)(Bs + r * 128 + (kb ^ ((r & 7) << 4)));
            }
#pragma unroll
            for (int mi = 0; mi < 4; ++mi)
#pragma unroll
                for (int ni = 0; ni < 4; ++ni)
                    acc[mi][ni] = __builtin_amdgcn_mfma_f32_16x16x32_bf16(af[mi], bfr[ni], acc[mi][ni], 0, 0, 0);
        }
    }
    // epilogue: bias+relu, store enc to global AND into LDS encL (swizzled A-tile)
    {
        float cb[4];
#pragma unroll
        for (int ni = 0; ni < 4; ++ni) cb[ni] = conv_b[wx * 64 + ni * 16 + ln];
        unsigned short* dst = encb + (size_t)t * (128 * 128);
#pragma unroll
        for (int mi = 0; mi < 4; ++mi)
#pragma unroll
            for (int jj = 0; jj < 4; ++jj) {
                int b = wy * 64 + mi * 16 + g * 4 + jj;
#pragma unroll
                for (int ni = 0; ni < 4; ++ni) {
                    int d = wx * 64 + ni * 16 + ln;
                    unsigned short us = f2b(fmaxf(acc[mi][ni][jj] + cb[ni], 0.f));
                    dst[b * 128 + d] = us;
                    *(unsigned short*)(encL + b * 256 + ((d * 2) ^ ((b & 7) << 4))) = us;
                }
            }
    }

    // Phase 2: gi N-tiles (n = nt*128 .. +128), A = encL, B staged into smem[0:32768]
    for (int nt = 0; nt < 3; ++nt) {
        __syncthreads();   // conv As/Bs reads done (nt=0) / prev B reads done
        {
            const unsigned short* bsrc = Wt + (size_t)nt * (128 * 128);
#pragma unroll
            for (int it = 0; it < 8; ++it) {
                int G = tid + it * 256;
                int r = G >> 4, go = G & 15;
                *(uint4*)(smem + (r * 16 + (go ^ (r & 7))) * 16) = *(const uint4*)(bsrc + r * 128 + go * 8);
            }
        }
        __syncthreads();   // B staged, encL complete

        f32x4 gacc[4][4];
#pragma unroll
        for (int i = 0; i < 4; ++i)
#pragma unroll
            for (int j = 0; j < 4; ++j) gacc[i][j] = (f32x4){0.f, 0.f, 0.f, 0.f};
#pragma unroll
        for (int ks = 0; ks < 4; ++ks) {
            bf16x8 af[4], bfr[4];
            const int kb = ks * 64 + g * 16;
#pragma unroll
            for (int mi = 0; mi < 4; ++mi) {
                int r = wy * 64 + mi * 16 + ln;
                af[mi] = *(const bf16x8*)(encL + r * 256 + (kb ^ ((r & 7) << 4)));
            }
#pragma unroll
            for (int ni = 0; ni < 4; ++ni) {
                int r = wx * 64 + ni * 16 + ln;
                bfr[ni] = *(const bf16x8*)(smem + r * 256 + (kb ^ ((r & 7) << 4)));
            }
#pragma unroll
            for (int mi = 0; mi < 4; ++mi)
#pragma unroll
                for (int ni = 0; ni < 4; ++ni)
                    gacc[mi][ni] = __builtin_amdgcn_mfma_f32_16x16x32_bf16(af[mi], bfr[ni], gacc[mi][ni], 0, 0, 0);
        }
        float bv[4];
#pragma unroll
        for (int ni = 0; ni < 4; ++ni) {
            int n = nt * 128 + wx * 64 + ni * 16 + ln;
            bv[ni] = b_ih[n] + (n < 256 ? b_hh[n] : 0.f);   // fold b_hh for r,z gates
        }
#pragma unroll
        for (int mi = 0; mi < 4; ++mi)
#pragma unroll
            for (int jj = 0; jj < 4; ++jj) {
                int m = t * 128 + wy * 64 + mi * 16 + g * 4 + jj;
#pragma unroll
                for (int ni = 0; ni < 4; ++ni) {
                    int n = nt * 128 + wx * 64 + ni * 16 + ln;
                    gi[(size_t)m * 384 + n] = gacc[mi][ni][jj] + bv[ni];
                }
            }
    }
}

// ---------------- GRU v10 (round-12 proven 141 us): dot2 + DPP + reg hold ----------
__global__ __launch_bounds__(512)
__attribute__((amdgpu_waves_per_eu(2, 2)))
void k_gru(const float* __restrict__ gi,
           const unsigned int* __restrict__ Whp,
           const float* __restrict__ bhh,
           unsigned short* __restrict__ ctxb,
           float* __restrict__ out_hidden) {
    const int b = blockIdx.x;
    const int tid = threadIdx.x;
    const int g = tid >> 2, q = tid & 3;
    __shared__ unsigned int hbuf[2][4][72];

    uint4 w0[4], w1[4], w2[4];
    {
        const unsigned int* W0 = Whp + (size_t)g * 64 + q * 16;
        const unsigned int* W1 = Whp + (size_t)(g + 128) * 64 + q * 16;
        const unsigned int* W2 = Whp + (size_t)(g + 256) * 64 + q * 16;
#pragma unroll
        for (int i = 0; i < 4; ++i) {
            w0[i] = ldg4u_pin(W0 + i * 4);
            w1[i] = ldg4u_pin(W1 + i * 4);
            w2[i] = ldg4u_pin(W2 + i * 4);
        }
    }
    const float bh2 = bhh[256 + g];   // only the n-gate bias stays (scaled by r)

    if (!(g & 1)) hbuf[0][q][g >> 1] = 0u;

    // depth-2 register prefetch of gate pre-activations (fp32)
    float p0r = gi[(size_t)b * 384 + g];
    float p0z = gi[(size_t)b * 384 + 128 + g];
    float p0n = gi[(size_t)b * 384 + 256 + g];
    float p1r = gi[((size_t)128 + b) * 384 + g];
    float p1z = gi[((size_t)128 + b) * 384 + 128 + g];
    float p1n = gi[((size_t)128 + b) * 384 + 256 + g];
    float hold = 0.f;                 // fp32 h[g] carried in-register (exact feedback)
    __syncthreads();

    for (int t = 0; t < 256; ++t) {
        const int cur = t & 1;
        float p2r = 0.f, p2z = 0.f, p2n = 0.f;
        if (t + 2 < 256) {
            const float* gp = gi + ((size_t)(t + 2) * 128 + b) * 384;
            p2r = gp[g]; p2z = gp[128 + g]; p2n = gp[256 + g];
        }

        // packed h window for this q (broadcast within q-group; q-groups bank-disjoint)
        const unsigned int* hc = &hbuf[cur][q][q * 16];
        uint4 h2[4];
#pragma unroll
        for (int i = 0; i < 4; ++i) h2[i] = *(const uint4*)(hc + i * 4);

        // 6 independent dot2 chains (3 gates x 2 halves)
        float a0 = 0.f, a1 = 0.f, a2 = 0.f, c0 = 0.f, c1 = 0.f, c2 = 0.f;
#pragma unroll
        for (int i = 0; i < 2; ++i) {
            dot2b(a0, w0[i].x, h2[i].x); dot2b(a1, w1[i].x, h2[i].x); dot2b(a2, w2[i].x, h2[i].x);
            dot2b(a0, w0[i].y, h2[i].y); dot2b(a1, w1[i].y, h2[i].y); dot2b(a2, w2[i].y, h2[i].y);
            dot2b(a0, w0[i].z, h2[i].z); dot2b(a1, w1[i].z, h2[i].z); dot2b(a2, w2[i].z, h2[i].z);
            dot2b(a0, w0[i].w, h2[i].w); dot2b(a1, w1[i].w, h2[i].w); dot2b(a2, w2[i].w, h2[i].w);
        }
#pragma unroll
        for (int i = 2; i < 4; ++i) {
            dot2b(c0, w0[i].x, h2[i].x); dot2b(c1, w1[i].x, h2[i].x); dot2b(c2, w2[i].x, h2[i].x);
            dot2b(c0, w0[i].y, h2[i].y); dot2b(c1, w1[i].y, h2[i].y); dot2b(c2, w2[i].y, h2[i].y);
            dot2b(c0, w0[i].z, h2[i].z); dot2b(c1, w1[i].z, h2[i].z); dot2b(c2, w2[i].z, h2[i].z);
            dot2b(c0, w0[i].w, h2[i].w); dot2b(c1, w1[i].w, h2[i].w); dot2b(c2, w2[i].w, h2[i].w);
        }
        a0 += c0; a1 += c1; a2 += c2;
        // DPP quad butterfly: all 4 q-lanes end with the full 128-k sum (VALU, no LDS pipe)
        a0 += dpp_xor1(a0); a0 += dpp_xor2(a0);
        a1 += dpp_xor1(a1); a1 += dpp_xor2(a1);
        a2 += dpp_xor1(a2); a2 += dpp_xor2(a2);

        // clamp-free gates: rcp saturates inf correctly; tanh needs only a lower guard
        float r = frcp(1.f + __expf(-(p0r + a0)));
        float z = frcp(1.f + __expf(-(p0z + a1)));
        float xn = p0n + r * (a2 + bh2);
        xn = fmaxf(xn, -20.f);
        float e2 = __expf(-2.f * xn);
        float n = (1.f - e2) * frcp(1.f + e2);
        float hnew = (1.f - z) * n + z * hold;
        hold = hnew;                                     // exact fp32 feedback

        // every q-lane writes its own rotated copy (b16 halfword, conflict-free)
        ((unsigned short*)&hbuf[cur ^ 1][q][0])[g] = f2b(hnew);
        if (q == 0) {
            ctxb[((size_t)t * 128 + b) * 128 + g] = f2b(hnew);
            if (t == 255) out_hidden[b * 128 + g] = hnew;
        }
        p0r = p1r; p0z = p1z; p0n = p1n;
        p1r = p2r; p1z = p2z; p1n = p2n;
        asm volatile("s_waitcnt lgkmcnt(0)" ::: "memory");
        __builtin_amdgcn_s_barrier();
    }
}

// ---------------- fused CPC: MFMA GEMM1 (P^T) -> MFMA GEMM2 (Sc) -> reg softmax ----------------
__global__ __launch_bounds__(256) void k_cpc(const unsigned short* __restrict__ ctxb,
                                             const unsigned short* __restrict__ encb,
                                             const unsigned short* __restrict__ pWb,
                                             const float* __restrict__ pb,
                                             float* __restrict__ lp,
                                             float* __restrict__ cp) {
    const int o = blockIdx.x, s = blockIdx.y;
    __shared__ __align__(16) char bufA[32768];   // ctx [c][d] -> later tgt [b][e]
    __shared__ __align__(16) char bufB[32768];   // Wo  [e][d] -> later P   [c][e]
    __shared__ float rowm[2][128], rowsum[2][128];
    __shared__ float Lrow[128], diagv[128];
    __shared__ float colv[2][128];
    __shared__ int   colix[2][128];
    __shared__ float fin[4];

    const int tid = threadIdx.x;
    const int lane = tid & 63, wid = tid >> 6;
    const int wy = wid >> 1, wx = wid & 1;
    const int g = lane >> 4, ln = lane & 15;

    {
        const unsigned short* src = ctxb + (size_t)(TIn + s) * (128 * 128);
        const unsigned short* wsrc = pWb + (size_t)o * (128 * 128);
#pragma unroll
        for (int it = 0; it < 8; ++it) {
            int G = tid + it * 256;
            int r = G >> 4, go = G & 15;
            *(uint4*)(bufA + (r * 16 + (go ^ (r & 7))) * 16) = *(const uint4*)(src + r * 128 + go * 8);
            *(uint4*)(bufB + (r * 16 + (go ^ (r & 7))) * 16) = *(const uint4*)(wsrc + r * 128 + go * 8);
        }
    }
    __syncthreads();

    // GEMM1: P^T[e][c] = Wo[e][:] . ctx[c][:]
    f32x4 acc[4][4];
#pragma unroll
    for (int i = 0; i < 4; ++i)
#pragma unroll
        for (int j = 0; j < 4; ++j) acc[i][j] = (f32x4){0.f, 0.f, 0.f, 0.f};
#pragma unroll
    for (int ks = 0; ks < 4; ++ks) {
        bf16x8 af[4], bfr[4];
        const int kb = ks * 64 + g * 16;
#pragma unroll
        for (int mi = 0; mi < 4; ++mi) {
            int r = wy * 64 + mi * 16 + ln;
            af[mi] = *(const bf16x8*)(bufB + r * 256 + (kb ^ ((r & 7) << 4)));
        }
#pragma unroll
        for (int ni = 0; ni < 4; ++ni) {
            int r = wx * 64 + ni * 16 + ln;
            bfr[ni] = *(const bf16x8*)(bufA + r * 256 + (kb ^ ((r & 7) << 4)));
        }
#pragma unroll
        for (int mi = 0; mi < 4; ++mi)
#pragma unroll
            for (int ni = 0; ni < 4; ++ni)
                acc[mi][ni] = __builtin_amdgcn_mfma_f32_16x16x32_bf16(af[mi], bfr[ni], acc[mi][ni], 0, 0, 0);
    }
    __syncthreads();

    // write P[c][e] (bias, bf16, swizzled) into bufB; stage tgt into bufA
    {
        float pbv[4][4];
#pragma unroll
        for (int mi = 0; mi < 4; ++mi) {
            int e0 = wy * 64 + mi * 16 + g * 4;
#pragma unroll
            for (int jj = 0; jj < 4; ++jj) pbv[mi][jj] = pb[o * 128 + e0 + jj];
        }
#pragma unroll
        for (int mi = 0; mi < 4; ++mi) {
            int e0 = wy * 64 + mi * 16 + g * 4;
#pragma unroll
            for (int ni = 0; ni < 4; ++ni) {
                int c = wx * 64 + ni * 16 + ln;
                unsigned int lo = pk2(acc[mi][ni][0] + pbv[mi][0], acc[mi][ni][1] + pbv[mi][1]);
                unsigned int hi = pk2(acc[mi][ni][2] + pbv[mi][2], acc[mi][ni][3] + pbv[mi][3]);
                int byteoff = c * 256 + ((e0 * 2) ^ ((c & 7) << 4));
                *(uint2*)(bufB + byteoff) = make_uint2(lo, hi);
            }
        }
        const unsigned short* tsrc = encb + (size_t)(TIn + 1 + o + s) * (128 * 128);
#pragma unroll
        for (int it = 0; it < 8; ++it) {
            int G = tid + it * 256;
            int r = G >> 4, go = G & 15;
            *(uint4*)(bufA + (r * 16 + (go ^ (r & 7))) * 16) = *(const uint4*)(tsrc + r * 128 + go * 8);
        }
    }
    __syncthreads();

    // GEMM2: Sc[b][c] = tgt[b][:] . P[c][:]
#pragma unroll
    for (int i = 0; i < 4; ++i)
#pragma unroll
        for (int j = 0; j < 4; ++j) acc[i][j] = (f32x4){0.f, 0.f, 0.f, 0.f};
#pragma unroll
    for (int ks = 0; ks < 4; ++ks) {
        bf16x8 af[4], bfr[4];
        const int kb = ks * 64 + g * 16;
#pragma unroll
        for (int mi = 0; mi < 4; ++mi) {
            int r = wy * 64 + mi * 16 + ln;
            af[mi] = *(const bf16x8*)(bufA + r * 256 + (kb ^ ((r & 7) << 4)));
        }
#pragma unroll
        for (int ni = 0; ni < 4; ++ni) {
            int r = wx * 64 + ni * 16 + ln;
            bfr[ni] = *(const bf16x8*)(bufB + r * 256 + (kb ^ ((r & 7) << 4)));
        }
#pragma unroll
        for (int mi = 0; mi < 4; ++mi)
#pragma unroll
            for (int ni = 0; ni < 4; ++ni)
                acc[mi][ni] = __builtin_amdgcn_mfma_f32_16x16x32_bf16(af[mi], bfr[ni], acc[mi][ni], 0, 0, 0);
    }

    // row softmax stats + diag, in-register
#pragma unroll
    for (int mi = 0; mi < 4; ++mi) {
#pragma unroll
        for (int jj = 0; jj < 4; ++jj) {
            float m = fmaxf(fmaxf(acc[mi][0][jj], acc[mi][1][jj]),
                            fmaxf(acc[mi][2][jj], acc[mi][3][jj]));
            m = fmaxf(m, __shfl_xor(m, 1)); m = fmaxf(m, __shfl_xor(m, 2));
            m = fmaxf(m, __shfl_xor(m, 4)); m = fmaxf(m, __shfl_xor(m, 8));
            float sm = __expf(acc[mi][0][jj] - m) + __expf(acc[mi][1][jj] - m)
                     + __expf(acc[mi][2][jj] - m) + __expf(acc[mi][3][jj] - m);
            sm += __shfl_xor(sm, 1); sm += __shfl_xor(sm, 2);
            sm += __shfl_xor(sm, 4); sm += __shfl_xor(sm, 8);
            int b = wy * 64 + mi * 16 + g * 4 + jj;
            if (ln == 0) { rowm[wx][b] = m; rowsum[wx][b] = sm; }
            if (wy == wx && ln == g * 4 + jj) diagv[b] = acc[mi][mi][jj];
        }
    }
    __syncthreads();
    if (tid < 128) {
        float m0 = rowm[0][tid], m1 = rowm[1][tid];
        float mm = fmaxf(m0, m1);
        float ss = rowsum[0][tid] * __expf(m0 - mm) + rowsum[1][tid] * __expf(m1 - mm);
        Lrow[tid] = mm + __logf(ss);
    }
    __syncthreads();

    float Lr[4][4];
#pragma unroll
    for (int mi = 0; mi < 4; ++mi)
#pragma unroll
        for (int jj = 0; jj < 4; ++jj) Lr[mi][jj] = Lrow[wy * 64 + mi * 16 + g * 4 + jj];

#pragma unroll
    for (int ni = 0; ni < 4; ++ni) {
        float best = NEG_INF; int bidx = 0x7fffffff;
#pragma unroll
        for (int mi = 0; mi < 4; ++mi)
#pragma unroll
            for (int jj = 0; jj < 4; ++jj) {
                float v = acc[mi][ni][jj] - Lr[mi][jj];
                int r = wy * 64 + mi * 16 + g * 4 + jj;
                if (v > best) { best = v; bidx = r; }
            }
#pragma unroll
        for (int mask = 16; mask <= 32; mask <<= 1) {
            float ov = __shfl_xor(best, mask);
            int   oi = __shfl_xor(bidx, mask);
            if (ov > best || (ov == best && oi < bidx)) { best = ov; bidx = oi; }
        }
        if (g == 0) {
            int c = wx * 64 + ni * 16 + ln;
            colv[wy][c] = best; colix[wy][c] = bidx;
        }
    }
    __syncthreads();

    float lsum = 0.f, csum = 0.f;
    if (tid < 128) {
        lsum = diagv[tid] - Lrow[tid];
        float v0 = colv[0][tid], v1 = colv[1][tid];
        int ix = (v1 > v0) ? colix[1][tid] : colix[0][tid];
        csum = (ix == tid) ? 1.f : 0.f;
    }
#pragma unroll
    for (int off = 32; off > 0; off >>= 1) {
        lsum += __shfl_down(lsum, off);
        csum += __shfl_down(csum, off);
    }
    if (lane == 0 && wid < 2) { fin[wid] = lsum; fin[2 + wid] = csum; }
    __syncthreads();
    if (tid == 0) {
        lp[o * Sn + s] = fin[0] + fin[1];
        cp[o * Sn + s] = fin[2] + fin[3];
    }
}

// ---------------- final reduction ----------------
__global__ __launch_bounds__(256) void k_final(const float* __restrict__ lp,
                                               const float* __restrict__ cp,
                                               float* __restrict__ out) {
    __shared__ float sl[256], sc2[256];
    const int tid = threadIdx.x;
    float l = 0.f, c = 0.f;
    for (int i = tid; i < TOn * Sn; i += 256) { l += lp[i]; c += cp[i]; }
    sl[tid] = l; sc2[tid] = c;
    __syncthreads();
    for (int s = 128; s > 0; s >>= 1) {
        if (tid < s) { sl[tid] += sl[tid + s]; sc2[tid] += sc2[tid + s]; }
        __syncthreads();
    }
    if (tid == 0) {
        out[0] = sc2[0] / DENOMF;      // accuracy
        out[1] = -sl[0] / DENOMF;      // loss
    }
}

extern "C" void kernel_launch(void* const* d_in, const int* in_sizes, int n_in,
                              void* d_out, int out_size, void* d_ws, size_t ws_size,
                              hipStream_t stream) {
    const float* X      = (const float*)d_in[0];
    const float* conv_w = (const float*)d_in[1];
    const float* conv_b = (const float*)d_in[2];
    const float* W_ih   = (const float*)d_in[3];
    const float* W_hh   = (const float*)d_in[4];
    const float* b_ih   = (const float*)d_in[5];
    const float* b_hh   = (const float*)d_in[6];
    const float* pred_W = (const float*)d_in[7];
    const float* pred_b = (const float*)d_in[8];
    float* out = (float*)d_out;
    char*  ws  = (char*)d_ws;

    unsigned short* encb = (unsigned short*)(ws + OFFB_ENC);
    unsigned short* ctxb = (unsigned short*)(ws + OFFB_CTX);
    float*          gi   = (float*)(ws + OFFB_GI);
    unsigned short* BcT  = (unsigned short*)(ws + OFFB_BCT);
    unsigned short* Wt   = (unsigned short*)(ws + OFFB_WT);
    float*          lp   = (float*)(ws + OFFB_LP);
    float*          cp   = (float*)(ws + OFFB_CP);
    unsigned int*   Whp  = (unsigned int*)(ws + OFFB_WHP);
    unsigned short* pWb  = (unsigned short*)(ws + OFFB_PWB);

    k_prep  <<<dim3(512),     dim3(256), 0, stream>>>(conv_w, BcT, W_ih, Wt, W_hh, Whp, pred_W, pWb);
    k_convgi<<<dim3(256),     dim3(256), 0, stream>>>(X, BcT, conv_b, Wt, b_ih, b_hh, encb, gi);
    k_gru   <<<dim3(128),     dim3(512), 0, stream>>>(gi, Whp, b_hh, ctxb, out + 2);
    k_cpc   <<<dim3(TOn, Sn), dim3(256), 0, stream>>>(ctxb, encb, pWb, pred_b, lp, cp);
    k_final <<<dim3(1),       dim3(256), 0, stream>>>(lp, cp, out);
}